// Round 1
// baseline (250.180 us; speedup 1.0000x reference)
//
#include <hip/hip_runtime.h>
#include <cmath>

constexpr int ISIZE = 512;
constexpr int REC   = 1024;
constexpr int NACT  = 18;
constexpr int BS    = 64;
constexpr float CLIPVAL = 2.0f;

// workspace layout (in floats)
constexpr size_t WS_W0T  = 0;                          // 512*1024 = W0 transposed [k][j]
constexpr size_t WS_PART = (size_t)ISIZE * REC;        // 64*9*1024 partial sums
constexpr size_t WS_G    = WS_PART + (size_t)BS * 9 * REC; // 64*1024 g[b][j]

// ---------------------------------------------------------------------------
// Transpose W0 [REC][ISIZE] -> W0t [ISIZE][REC] so the x@W0^T partial kernel
// can stream it coalesced with float4.
__global__ __launch_bounds__(256) void k_transpose_w0(
    const float* __restrict__ W0, float* __restrict__ W0t) {
  __shared__ float tile[32][33];
  const int bx = blockIdx.x;  // k-tile: ISIZE/32 = 16
  const int by = blockIdx.y;  // j-tile: REC/32  = 32
  const int tx = threadIdx.x; // 0..31
  const int ty = threadIdx.y; // 0..7
#pragma unroll
  for (int r = 0; r < 32; r += 8)
    tile[ty + r][tx] = W0[(size_t)(by * 32 + ty + r) * ISIZE + bx * 32 + tx];
  __syncthreads();
#pragma unroll
  for (int r = 0; r < 32; r += 8)
    W0t[(size_t)(bx * 32 + ty + r) * REC + by * 32 + tx] = tile[tx][ty + r];
}

// ---------------------------------------------------------------------------
// Partial sums for rec_in[b,j] = sum_i rv[b,i]*(w[i,j] + alpha[i,j]*hebb[b,i,j])
// plus (chunk 8) the input contribution sum_k x[b,k]*W0t[k,j].
// grid: (9, BS); block: 256 threads; thread owns 4 consecutive j (float4).
__global__ __launch_bounds__(256) void k_partial(
    const float* __restrict__ rv, const float* __restrict__ hebb,
    const float* __restrict__ w, const float* __restrict__ alpha,
    const float* __restrict__ x, const float* __restrict__ w0t,
    float* __restrict__ part) {
  const int ic = blockIdx.x;        // 0..8
  const int b  = blockIdx.y;        // 0..BS-1
  const int j0 = threadIdx.x * 4;   // 0..1020
  float4 acc = make_float4(0.f, 0.f, 0.f, 0.f);

  if (ic < 8) {
    const int i0 = ic * 128;
    const float* __restrict__ rvb = rv + (size_t)b * REC;
    const size_t hb = (size_t)b * REC * REC;
#pragma unroll 4
    for (int i = i0; i < i0 + 128; ++i) {
      const float r = rvb[i];
      const float4 wv = *reinterpret_cast<const float4*>(w     + (size_t)i * REC + j0);
      const float4 av = *reinterpret_cast<const float4*>(alpha + (size_t)i * REC + j0);
      const float4 hv = *reinterpret_cast<const float4*>(hebb + hb + (size_t)i * REC + j0);
      acc.x = fmaf(r, fmaf(av.x, hv.x, wv.x), acc.x);
      acc.y = fmaf(r, fmaf(av.y, hv.y, wv.y), acc.y);
      acc.z = fmaf(r, fmaf(av.z, hv.z, wv.z), acc.z);
      acc.w = fmaf(r, fmaf(av.w, hv.w, wv.w), acc.w);
    }
  } else {
    const float* __restrict__ xb = x + (size_t)b * ISIZE;
#pragma unroll 4
    for (int k = 0; k < ISIZE; ++k) {
      const float xv = xb[k];
      const float4 wv = *reinterpret_cast<const float4*>(w0t + (size_t)k * REC + j0);
      acc.x = fmaf(xv, wv.x, acc.x);
      acc.y = fmaf(xv, wv.y, acc.y);
      acc.z = fmaf(xv, wv.z, acc.z);
      acc.w = fmaf(xv, wv.w, acc.w);
    }
  }
  *reinterpret_cast<float4*>(part + ((size_t)b * 9 + ic) * REC + j0) = acc;
}

// ---------------------------------------------------------------------------
// hactiv[b,j] = tanh(b0[j] + sum over 9 partials)
__global__ __launch_bounds__(256) void k_hactiv(
    const float* __restrict__ part, const float* __restrict__ b0,
    float* __restrict__ hact) {
  const int b  = blockIdx.x;
  const int j0 = threadIdx.x * 4;
  float4 s = *reinterpret_cast<const float4*>(b0 + j0);
#pragma unroll
  for (int ic = 0; ic < 9; ++ic) {
    const float4 p = *reinterpret_cast<const float4*>(part + ((size_t)b * 9 + ic) * REC + j0);
    s.x += p.x; s.y += p.y; s.z += p.z; s.w += p.w;
  }
  float4 o;
  o.x = tanhf(s.x); o.y = tanhf(s.y); o.z = tanhf(s.z); o.w = tanhf(s.w);
  *reinterpret_cast<float4*>(hact + (size_t)b * REC + j0) = o;
}

// ---------------------------------------------------------------------------
// Per-batch head: logits -> softmax, myeta -> g[b,j] = (myeta*mw[j]+mb[j])*hact[b,j]
// grid: BS blocks; block: 256 threads.
__global__ __launch_bounds__(256) void k_head(
    const float* __restrict__ hact, const float* __restrict__ W1,
    const float* __restrict__ b1, const float* __restrict__ h2w,
    const float* __restrict__ h2b, const float* __restrict__ mw,
    const float* __restrict__ mb, float* __restrict__ act_dis,
    float* __restrict__ g) {
  const int b = blockIdx.x;
  const int t = threadIdx.x;
  const float* __restrict__ h = hact + (size_t)b * REC;
  __shared__ float red[256];
  __shared__ float logits[NACT];
  __shared__ float myeta_s;

  for (int a = 0; a < NACT; ++a) {
    float p = 0.f;
    for (int j = t; j < REC; j += 256) p = fmaf(h[j], W1[(size_t)a * REC + j], p);
    red[t] = p; __syncthreads();
    for (int s = 128; s > 0; s >>= 1) {
      if (t < s) red[t] += red[t + s];
      __syncthreads();
    }
    if (t == 0) logits[a] = red[0] + b1[a];
    __syncthreads();
  }

  {
    float p = 0.f;
    for (int j = t; j < REC; j += 256) p = fmaf(h[j], h2w[j], p);
    red[t] = p; __syncthreads();
    for (int s = 128; s > 0; s >>= 1) {
      if (t < s) red[t] += red[t + s];
      __syncthreads();
    }
    if (t == 0) myeta_s = tanhf(red[0] + h2b[0]);
  }
  __syncthreads();

  if (t == 0) {
    float m = logits[0];
    for (int a = 1; a < NACT; ++a) m = fmaxf(m, logits[a]);
    float e[NACT];
    float ssum = 0.f;
    for (int a = 0; a < NACT; ++a) { e[a] = expf(logits[a] - m); ssum += e[a]; }
    const float inv = 1.f / ssum;
    for (int a = 0; a < NACT; ++a) act_dis[(size_t)b * NACT + a] = e[a] * inv;
  }

  const float me = myeta_s;
  for (int j = t; j < REC; j += 256)
    g[(size_t)b * REC + j] = fmaf(me, mw[j], mb[j]) * h[j];
}

// ---------------------------------------------------------------------------
// hebb_out[b,i,j] = clip(hebb[b,i,j] + rv[b,i]*g[b,j], -CLIP, CLIP)
// grid: (REC/8, BS); block 256; each block does 8 rows, g row loaded once.
__global__ __launch_bounds__(256) void k_hebb(
    const float* __restrict__ hebb, const float* __restrict__ rv,
    const float* __restrict__ g, float* __restrict__ out) {
  const int b  = blockIdx.y;
  const int i0 = blockIdx.x * 8;
  const int j0 = threadIdx.x * 4;
  const float4 gv = *reinterpret_cast<const float4*>(g + (size_t)b * REC + j0);
  const float* __restrict__ rvb = rv + (size_t)b * REC;
  const size_t hb = (size_t)b * REC * REC;
#pragma unroll
  for (int ii = 0; ii < 8; ++ii) {
    const int i = i0 + ii;
    const float r = rvb[i];
    const size_t off = hb + (size_t)i * REC + j0;
    const float4 hv = *reinterpret_cast<const float4*>(hebb + off);
    float4 o;
    o.x = fminf(fmaxf(fmaf(r, gv.x, hv.x), -CLIPVAL), CLIPVAL);
    o.y = fminf(fmaxf(fmaf(r, gv.y, hv.y), -CLIPVAL), CLIPVAL);
    o.z = fminf(fmaxf(fmaf(r, gv.z, hv.z), -CLIPVAL), CLIPVAL);
    o.w = fminf(fmaxf(fmaf(r, gv.w, hv.w), -CLIPVAL), CLIPVAL);
    *reinterpret_cast<float4*>(out + off) = o;
  }
}

// ---------------------------------------------------------------------------
extern "C" void kernel_launch(void* const* d_in, const int* in_sizes, int n_in,
                              void* d_out, int out_size, void* d_ws, size_t ws_size,
                              hipStream_t stream) {
  const float* x     = (const float*)d_in[0];   // [64][512]
  const float* rv    = (const float*)d_in[1];   // [64][1024]
  const float* hebb  = (const float*)d_in[2];   // [64][1024][1024]
  const float* w     = (const float*)d_in[3];   // [1024][1024]
  const float* alpha = (const float*)d_in[4];   // [1024][1024]
  const float* W0    = (const float*)d_in[5];   // [1024][512]
  const float* b0    = (const float*)d_in[6];   // [1024]
  const float* W1    = (const float*)d_in[7];   // [18][1024]
  const float* b1    = (const float*)d_in[8];   // [18]
  const float* h2w   = (const float*)d_in[9];   // [1][1024]
  const float* h2b   = (const float*)d_in[10];  // [1]
  const float* mw    = (const float*)d_in[11];  // [1024][1]
  const float* mb    = (const float*)d_in[12];  // [1024]

  float* out_act  = (float*)d_out;               // 64*18
  float* out_hact = out_act + (size_t)BS * NACT; // 64*1024
  float* out_hebb = out_hact + (size_t)BS * REC; // 64*1024*1024

  float* ws   = (float*)d_ws;
  float* w0t  = ws + WS_W0T;
  float* part = ws + WS_PART;
  float* g    = ws + WS_G;

  k_transpose_w0<<<dim3(ISIZE / 32, REC / 32), dim3(32, 8), 0, stream>>>(W0, w0t);
  k_partial<<<dim3(9, BS), 256, 0, stream>>>(rv, hebb, w, alpha, x, w0t, part);
  k_hactiv<<<BS, 256, 0, stream>>>(part, b0, out_hact);
  k_head<<<BS, 256, 0, stream>>>(out_hact, W1, b1, h2w, h2b, mw, mb, out_act, g);
  k_hebb<<<dim3(REC / 8, BS), 256, 0, stream>>>(hebb, rv, g, out_hebb);
}